// Round 3
// baseline (155.138 us; speedup 1.0000x reference)
//
#include <hip/hip_runtime.h>
#include <hip/hip_bf16.h>
#include <math.h>

typedef __attribute__((ext_vector_type(8))) short short8v;
typedef __attribute__((ext_vector_type(4))) float float4v;

#define TB 128   // targets per block (4 waves x 32 targets)

__device__ __forceinline__ short f2bf(float f) {
    __hip_bfloat16 h = __float2bfloat16(f);
    short s; __builtin_memcpy(&s, &h, sizeof(short));
    return s;
}
__device__ __forceinline__ float4v mfma_bf16(short8v a, short8v b, float4v c) {
    return __builtin_amdgcn_mfma_f32_16x16x32_bf16(a, b, c, 0, 0, 0);
}

__global__ __launch_bounds__(256)
void copy_x_kernel(const float4* __restrict__ x, float4* __restrict__ out, int n4) {
    int i = blockIdx.x * blockDim.x + threadIdx.x;
    if (i < n4) out[i] = x[i];
}

// Block = 256 threads (4 waves), TB=128 consecutive targets; wave owns 32 targets
// = 256 point rows = 16 m-tiles of mfma_16x16x32.
// Softmax: feat_px part + sm_b are segment-constant -> cancel. logits = ptx@sm_w[:64]
// as B col-tile 4 (smw | zero pad). ptx_out = ptx@W1 + q[t], q = fpx@W2 + fo_b,
// q kept in registers (fragment shuffles in epilogue).
__global__ __launch_bounds__(256, 3)
void fused_kernel(const float* __restrict__ x,
                  const float* __restrict__ ptx,
                  const float* __restrict__ sm_w,
                  const float* __restrict__ fo_w,
                  const float* __restrict__ fo_b,
                  const int* __restrict__ point_key,
                  const int* __restrict__ pixel_tgt_idx,
                  float* __restrict__ xout,
                  float* __restrict__ ptx_out,
                  int n_tgt, int n_pts, int hw)
{
    // fpx[128][72] bf16 (18432 B) + wT[128][72] bf16 (18432 B); agg[128][68] f32
    // (34816 B) overlays both after they are consumed.
    __shared__ __align__(16) char sraw[2 * 128 * 72 * 2];
    unsigned short (*fpx)[72] = (unsigned short (*)[72])sraw;
    unsigned short (*wT)[72]  = (unsigned short (*)[72])(sraw + 128 * 72 * 2);
    float (*agg)[68]          = (float (*)[68])sraw;
    __shared__ int pix_s[TB], r0_s[TB], deg_s[TB];

    const int tid  = threadIdx.x;
    const int lane = tid & 63;
    const int w    = tid >> 6;
    const int lo16 = lane & 15;
    const int g    = lane >> 4;
    const int t0   = blockIdx.x * TB;

    // ---- S1: per-target metadata + weight staging (fo_w -> wT, bf16, transposed) ----
    if (tid < TB) {
        int t = t0 + tid;
        bool v = t < n_tgt;
        int r0 = v ? point_key[t] : 0;
        int d  = v ? (point_key[t + 1] - r0) : 0;
        pix_s[tid] = v ? pixel_tgt_idx[t] : 0;
        r0_s[tid]  = r0;
        deg_s[tid] = d > 8 ? 8 : d;
    }
    {
        const float4* fw4 = (const float4*)fo_w;   // 2048 float4s, coalesced
        #pragma unroll
        for (int i = 0; i < 8; ++i) {
            int idx4 = i * 256 + tid;
            float4 v = fw4[idx4];
            int flat = idx4 * 4;
            int k = flat >> 6, c = flat & 63;
            int wrow0 = (k & 64) + c;              // W1 -> rows 0..63, W2 -> 64..127
            int col = k & 63;
            wT[wrow0 + 0][col] = (unsigned short)f2bf(v.x);
            wT[wrow0 + 1][col] = (unsigned short)f2bf(v.y);
            wT[wrow0 + 2][col] = (unsigned short)f2bf(v.z);
            wT[wrow0 + 3][col] = (unsigned short)f2bf(v.w);
        }
    }
    __syncthreads();

    // ---- S2: fpx gather (2 threads/target, coalesced per channel plane) + B1 frags ----
    {
        const int tgt = tid >> 1, half = tid & 1;
        const int pix = pix_s[tgt];
        const float* xp = x + (size_t)(half * 32) * hw + pix;
        #pragma unroll
        for (int ch = 0; ch < 4; ++ch) {
            short8v pk;
            #pragma unroll
            for (int j = 0; j < 8; ++j)
                pk[j] = f2bf(xp[(size_t)(ch * 8 + j) * hw]);
            *(short8v*)&fpx[tgt][half * 32 + ch * 8] = pk;   // min-cost b128 writes
        }
    }
    short8v b1[5][2];
    #pragma unroll
    for (int ct = 0; ct < 4; ++ct)
        #pragma unroll
        for (int kh = 0; kh < 2; ++kh)
            b1[ct][kh] = *(const short8v*)&wT[ct * 16 + lo16][kh * 32 + g * 8];
    #pragma unroll
    for (int kh = 0; kh < 2; ++kh) {               // logit column: smw | zeros
        short8v bb;
        #pragma unroll
        for (int j = 0; j < 8; ++j)
            bb[j] = (lo16 == 0) ? f2bf(sm_w[kh * 32 + g * 8 + j]) : (short)0;
        b1[4][kh] = bb;
    }
    float fb[4];
    #pragma unroll
    for (int ct = 0; ct < 4; ++ct) fb[ct] = fo_b[ct * 16 + lo16];
    __syncthreads();

    // ---- S3: q-GEMM for this wave's 32 targets; q stays in registers ----
    const int tw0 = w * 32;
    float4v qreg[2][4];
    {
        short8v a2[2][2];
        #pragma unroll
        for (int mq = 0; mq < 2; ++mq)
            #pragma unroll
            for (int kh = 0; kh < 2; ++kh)
                a2[mq][kh] = *(const short8v*)&fpx[tw0 + mq * 16 + lo16][kh * 32 + g * 8];
        #pragma unroll
        for (int ct = 0; ct < 4; ++ct) {
            short8v b20 = *(const short8v*)&wT[64 + ct * 16 + lo16][g * 8];
            short8v b21 = *(const short8v*)&wT[64 + ct * 16 + lo16][32 + g * 8];
            #pragma unroll
            for (int mq = 0; mq < 2; ++mq) {
                float4v z = {0.f, 0.f, 0.f, 0.f};
                z = mfma_bf16(a2[mq][0], b20, z);
                z = mfma_bf16(a2[mq][1], b21, z);
                #pragma unroll
                for (int r = 0; r < 4; ++r) qreg[mq][ct][r] = z[r] + fb[ct];
            }
        }
    }
    __syncthreads();   // fpx/wT dead; agg may overwrite

    // ---- S4: main loop, 16 m-tiles (mq unrolled so qreg indices stay static) ----
    #pragma unroll
    for (int mq = 0; mq < 2; ++mq)
    for (int mtl2 = 0; mtl2 < 4; ++mtl2) {
        #pragma unroll
        for (int u = 0; u < 2; ++u) {
            const int mt  = mq * 8 + mtl2 * 2 + u;
            const int tlA = tw0 + mt * 2 + (lo16 >> 3);
            int pg = r0_s[tlA] + (lo16 & 7);
            if (pg >= n_pts) pg = n_pts - 1;
            const float* prow = ptx + (size_t)pg * 64 + g * 8;
            short8v a[2];
            #pragma unroll
            for (int kh = 0; kh < 2; ++kh) {
                float4 f0 = *(const float4*)(prow + kh * 32);
                float4 f1 = *(const float4*)(prow + kh * 32 + 4);
                short8v aa;
                aa[0] = f2bf(f0.x); aa[1] = f2bf(f0.y); aa[2] = f2bf(f0.z); aa[3] = f2bf(f0.w);
                aa[4] = f2bf(f1.x); aa[5] = f2bf(f1.y); aa[6] = f2bf(f1.z); aa[7] = f2bf(f1.w);
                a[kh] = aa;
            }
            float4v c[5];
            #pragma unroll
            for (int ct = 0; ct < 5; ++ct) {
                float4v z = {0.f, 0.f, 0.f, 0.f};
                z = mfma_bf16(a[0], b1[ct][0], z);
                c[ct] = mfma_bf16(a[1], b1[ct][1], z);
            }

            // epilogue: lane -> target tE, points pE=(g&1)*4+r
            const int tE   = tw0 + mt * 2 + (g >> 1);
            const int degE = deg_s[tE];
            const int r0E  = r0_s[tE];
            float lgt[4];
            #pragma unroll
            for (int r = 0; r < 4; ++r) {
                float v = __shfl(c[4][r], lane & 48);
                lgt[r] = (((g & 1) * 4 + r) < degE) ? v : -3.4e38f;
            }
            float m4 = fmaxf(fmaxf(lgt[0], lgt[1]), fmaxf(lgt[2], lgt[3]));
            float m8 = fmaxf(m4, __shfl_xor(m4, 16));
            float wgt[4], wsum = 0.f;
            #pragma unroll
            for (int r = 0; r < 4; ++r) {
                int pE = (g & 1) * 4 + r;
                wgt[r] = (pE < degE) ? __expf(lgt[r] - m8) : 0.0f;
                wsum += wgt[r];
            }
            wsum += __shfl_xor(wsum, 16);
            const float inv = 1.0f / (wsum + 1e-16f);

            // q for rows R0=4*mtl2+2u (g<2) / R0+1 (g>=2), held by lane group mtl2
            const int srcLane = mtl2 * 16 + lo16;
            #pragma unroll
            for (int ct = 0; ct < 4; ++ct) {
                float q0 = __shfl(qreg[mq][ct][2 * u],     srcLane);
                float q1 = __shfl(qreg[mq][ct][2 * u + 1], srcLane);
                float qv = (g & 2) ? q1 : q0;
                int col = ct * 16 + lo16;
                float ap = 0.f;
                #pragma unroll
                for (int r = 0; r < 4; ++r) {
                    float po = c[ct][r] + qv;
                    int pE = (g & 1) * 4 + r;
                    if (pE < degE)
                        ptx_out[(size_t)(r0E + pE) * 64 + col] = po;
                    ap = fmaf(wgt[r] * inv, po, ap);
                }
                ap += __shfl_xor(ap, 16);
                if (!(lane & 16)) agg[tE][col] = ap;   // groups 0,2 hold both sums
            }
        }
    }
    __syncthreads();

    // ---- S5: xout write-back (2 threads/target, coalesced per channel plane) ----
    {
        const int tgt = tid >> 1, half = tid & 1;
        if (t0 + tgt < n_tgt) {
            const int pix = pix_s[tgt];
            float* xp = xout + (size_t)(half * 32) * hw + pix;
            #pragma unroll
            for (int ch = 0; ch < 8; ++ch) {
                float4 v = *(const float4*)&agg[tgt][half * 32 + ch * 4];
                xp[(size_t)(ch * 4 + 0) * hw] = v.x;
                xp[(size_t)(ch * 4 + 1) * hw] = v.y;
                xp[(size_t)(ch * 4 + 2) * hw] = v.z;
                xp[(size_t)(ch * 4 + 3) * hw] = v.w;
            }
        }
    }
}

extern "C" void kernel_launch(void* const* d_in, const int* in_sizes, int n_in,
                              void* d_out, int out_size, void* d_ws, size_t ws_size,
                              hipStream_t stream) {
    const float* x             = (const float*)d_in[0];
    const float* ptx           = (const float*)d_in[1];
    const float* sm_w          = (const float*)d_in[2];
    // d_in[3] = sm_b: segment-constant logit shift, cancels in softmax
    const float* fo_w          = (const float*)d_in[4];
    const float* fo_b          = (const float*)d_in[5];
    const int*   point_key     = (const int*)d_in[6];
    const int*   pixel_tgt_idx = (const int*)d_in[7];

    const int x_elems = in_sizes[0];          // 64 * H * W
    const int hw      = x_elems / 64;
    const int n_tgt   = in_sizes[7];
    const int n_pts   = in_sizes[1] / 64;

    float* xout    = (float*)d_out;
    float* ptx_out = xout + (size_t)x_elems;

    const int n4 = x_elems / 4;
    copy_x_kernel<<<(n4 + 255) / 256, 256, 0, stream>>>(
        (const float4*)x, (float4*)xout, n4);

    const int blocks = (n_tgt + TB - 1) / TB;
    fused_kernel<<<blocks, 256, 0, stream>>>(
        x, ptx, sm_w, fo_w, fo_b, point_key, pixel_tgt_idx,
        xout, ptx_out, n_tgt, n_pts, hw);
}

// Round 4
// 142.998 us; speedup vs baseline: 1.0849x; 1.0849x over previous
//
#include <hip/hip_runtime.h>
#include <hip/hip_bf16.h>
#include <math.h>

typedef __attribute__((ext_vector_type(8))) short short8v;
typedef __attribute__((ext_vector_type(4))) float float4v;

#define TB 64   // targets per block (4 waves x 16 targets)

__device__ __forceinline__ short f2bf(float f) {
    __hip_bfloat16 h = __float2bfloat16(f);
    short s; __builtin_memcpy(&s, &h, sizeof(short));
    return s;
}
__device__ __forceinline__ float4v mfma_bf16(short8v a, short8v b, float4v c) {
    return __builtin_amdgcn_mfma_f32_16x16x32_bf16(a, b, c, 0, 0, 0);
}

__global__ __launch_bounds__(256)
void copy_x_kernel(const float4* __restrict__ x, float4* __restrict__ out, int n4) {
    int i = blockIdx.x * blockDim.x + threadIdx.x;
    if (i < n4) out[i] = x[i];
}

// Block = 256 threads (4 waves), TB=64 targets; wave owns 16 targets = 128 point
// rows = 8 m-tiles of mfma_16x16x32. Softmax: feat_px part + sm_b are
// segment-constant -> cancel; logits = ptx@sm_w[:64] as B col-tile 4.
// ptx_out = ptx@W1 + q[t], q = fpx@W2 + fo_b (q_lds overlays dead fpx/wT).
__global__ __launch_bounds__(256, 4)
void fused_kernel(const float* __restrict__ x,
                  const float* __restrict__ ptx,
                  const float* __restrict__ sm_w,
                  const float* __restrict__ fo_w,
                  const float* __restrict__ fo_b,
                  const int* __restrict__ point_key,
                  const int* __restrict__ pixel_tgt_idx,
                  float* __restrict__ xout,
                  float* __restrict__ ptx_out,
                  int n_tgt, int n_pts, int hw)
{
    // phase 1: fpx[64][72]u16 (9216B) + wT[128][72]u16 (18432B)  = 27648B
    // phase 2 overlay: q_lds[64][68]f32 (17408B) + agg[64][68]f32 (17408B) = 34816B
    __shared__ __align__(16) char sraw[34816];
    unsigned short (*fpx)[72] = (unsigned short (*)[72])sraw;
    unsigned short (*wT)[72]  = (unsigned short (*)[72])(sraw + 9216);
    float (*q_lds)[68]        = (float (*)[68])sraw;
    float (*agg)[68]          = (float (*)[68])(sraw + 17408);
    __shared__ int pix_s[TB], r0_s[TB], deg_s[TB];

    const int tid  = threadIdx.x;
    const int lane = tid & 63;
    const int w    = tid >> 6;
    const int lo16 = lane & 15;
    const int g    = lane >> 4;
    const int t0   = blockIdx.x * TB;
    const int tw0  = w * 16;              // wave's first local target

    // ---- S0: issue weight loads early (independent of meta) ----
    float4 wv[8];
    {
        const float4* fw4 = (const float4*)fo_w;   // 2048 float4, coalesced
        #pragma unroll
        for (int i = 0; i < 8; ++i) wv[i] = fw4[i * 256 + tid];
    }
    if (tid < TB) {
        int t = t0 + tid;
        bool v = t < n_tgt;
        int r0 = v ? point_key[t] : 0;
        int d  = v ? (point_key[t + 1] - r0) : 0;
        pix_s[tid] = v ? pixel_tgt_idx[t] : 0;
        r0_s[tid]  = r0;
        deg_s[tid] = d > 8 ? 8 : d;
    }
    float fb[4];
    #pragma unroll
    for (int ct = 0; ct < 4; ++ct) fb[ct] = fo_b[ct * 16 + lo16];

    // ---- S1: wT staging (bf16, transposed [cout|cin_px][k]) ----
    #pragma unroll
    for (int i = 0; i < 8; ++i) {
        int flat = (i * 256 + tid) * 4;
        int k = flat >> 6, c = flat & 63;
        int wrow0 = (k & 64) + c;          // W1 -> rows 0..63, W2 -> 64..127
        int col = k & 63;
        wT[wrow0 + 0][col] = (unsigned short)f2bf(wv[i].x);
        wT[wrow0 + 1][col] = (unsigned short)f2bf(wv[i].y);
        wT[wrow0 + 2][col] = (unsigned short)f2bf(wv[i].z);
        wT[wrow0 + 3][col] = (unsigned short)f2bf(wv[i].w);
    }
    __syncthreads();   // meta + wT visible

    // ---- S2: fpx gather (4 threads/target, coalesced per channel plane) ----
    {
        const int tgt = tid >> 2, q4 = tid & 3;
        const int pix = pix_s[tgt];
        const float* xp = x + (size_t)(q4 * 16) * hw + pix;
        #pragma unroll
        for (int hhalf = 0; hhalf < 2; ++hhalf) {
            short8v pk;
            #pragma unroll
            for (int j = 0; j < 8; ++j)
                pk[j] = f2bf(xp[(size_t)(hhalf * 8 + j) * hw]);
            *(short8v*)&fpx[tgt][q4 * 16 + hhalf * 8] = pk;
        }
    }

    // B1 fragments: [W1 | smw | zeros], 5 col-tiles x 2 K-halves (regs, reused 8x)
    short8v b1[5][2];
    #pragma unroll
    for (int ct = 0; ct < 4; ++ct)
        #pragma unroll
        for (int kh = 0; kh < 2; ++kh)
            b1[ct][kh] = *(const short8v*)&wT[ct * 16 + lo16][kh * 32 + g * 8];
    #pragma unroll
    for (int kh = 0; kh < 2; ++kh) {
        short8v bb;
        #pragma unroll
        for (int j = 0; j < 8; ++j)
            bb[j] = (lo16 == 0) ? f2bf(sm_w[kh * 32 + g * 8 + j]) : (short)0;
        b1[4][kh] = bb;
    }
    __syncthreads();   // fpx visible

    // ---- S3: q-GEMM (wave's 16 targets), then park q in LDS overlay ----
    float4v qv4[4];
    {
        short8v a20 = *(const short8v*)&fpx[tw0 + lo16][g * 8];
        short8v a21 = *(const short8v*)&fpx[tw0 + lo16][32 + g * 8];
        #pragma unroll
        for (int ct = 0; ct < 4; ++ct) {
            short8v b20 = *(const short8v*)&wT[64 + ct * 16 + lo16][g * 8];
            short8v b21 = *(const short8v*)&wT[64 + ct * 16 + lo16][32 + g * 8];
            float4v z = {0.f, 0.f, 0.f, 0.f};
            z = mfma_bf16(a20, b20, z);
            qv4[ct] = mfma_bf16(a21, b21, z);
        }
    }
    __syncthreads();   // all waves done with fpx/wT -> overlays live
    #pragma unroll
    for (int ct = 0; ct < 4; ++ct)
        #pragma unroll
        for (int r = 0; r < 4; ++r)
            q_lds[tw0 + g * 4 + r][ct * 16 + lo16] = qv4[ct][r] + fb[ct];
    // wave-local: each wave reads back only its own rows -> no barrier

    // ---- S4: main loop, 8 m-tiles, depth-1 A prefetch ----
    float4 buf0, buf1, buf2, buf3;
    auto LOADA = [&](int mt) {
        const int tlA = tw0 + mt * 2 + (lo16 >> 3);
        int pg = r0_s[tlA] + (lo16 & 7);
        if (pg >= n_pts) pg = n_pts - 1;
        const float* prow = ptx + (size_t)pg * 64 + g * 8;
        buf0 = *(const float4*)(prow);
        buf1 = *(const float4*)(prow + 4);
        buf2 = *(const float4*)(prow + 32);
        buf3 = *(const float4*)(prow + 36);
    };
    LOADA(0);
    #pragma unroll
    for (int mt = 0; mt < 8; ++mt) {
        const float4 c0 = buf0, c1 = buf1, c2 = buf2, c3 = buf3;
        if (mt < 7) LOADA(mt + 1);           // overlap with MFMA + epilogue

        short8v a0, a1;
        a0[0] = f2bf(c0.x); a0[1] = f2bf(c0.y); a0[2] = f2bf(c0.z); a0[3] = f2bf(c0.w);
        a0[4] = f2bf(c1.x); a0[5] = f2bf(c1.y); a0[6] = f2bf(c1.z); a0[7] = f2bf(c1.w);
        a1[0] = f2bf(c2.x); a1[1] = f2bf(c2.y); a1[2] = f2bf(c2.z); a1[3] = f2bf(c2.w);
        a1[4] = f2bf(c3.x); a1[5] = f2bf(c3.y); a1[6] = f2bf(c3.z); a1[7] = f2bf(c3.w);

        float4v c[5];
        #pragma unroll
        for (int ct = 0; ct < 5; ++ct) {
            float4v z = {0.f, 0.f, 0.f, 0.f};
            z = mfma_bf16(a0, b1[ct][0], z);
            c[ct] = mfma_bf16(a1, b1[ct][1], z);
        }

        // epilogue: lane -> target tE (local), points pE=(g&1)*4+r
        const int tE   = tw0 + mt * 2 + (g >> 1);
        const int degE = deg_s[tE];
        const int r0E  = r0_s[tE];
        float lgt[4];
        #pragma unroll
        for (int r = 0; r < 4; ++r) {
            float v = __shfl(c[4][r], lane & 48);   // logit col (64) from lo16==0
            lgt[r] = (((g & 1) * 4 + r) < degE) ? v : -3.4e38f;
        }
        float m4 = fmaxf(fmaxf(lgt[0], lgt[1]), fmaxf(lgt[2], lgt[3]));
        float m8 = fmaxf(m4, __shfl_xor(m4, 16));
        float wgt[4], wsum = 0.f;
        #pragma unroll
        for (int r = 0; r < 4; ++r) {
            int pE = (g & 1) * 4 + r;
            wgt[r] = (pE < degE) ? __expf(lgt[r] - m8) : 0.0f;
            wsum += wgt[r];
        }
        wsum += __shfl_xor(wsum, 16);
        const float inv = 1.0f / (wsum + 1e-16f);

        #pragma unroll
        for (int ct = 0; ct < 4; ++ct) {
            const int col = ct * 16 + lo16;
            const float qv = q_lds[tE][col];
            float ap = 0.f;
            #pragma unroll
            for (int r = 0; r < 4; ++r) {
                float po = c[ct][r] + qv;
                int pE = (g & 1) * 4 + r;
                if (pE < degE)
                    ptx_out[(size_t)(r0E + pE) * 64 + col] = po;
                ap = fmaf(wgt[r] * inv, po, ap);
            }
            ap += __shfl_xor(ap, 16);
            if (!(lane & 16)) agg[tE][col] = ap;   // groups 0,2 hold both targets
        }
    }
    __syncthreads();

    // ---- S5: xout write-back (4 threads/target, coalesced per channel plane) ----
    {
        const int tgt = tid >> 2, q4 = tid & 3;
        if (t0 + tgt < n_tgt) {
            const int pix = pix_s[tgt];
            float* xp = xout + (size_t)(q4 * 16) * hw + pix;
            #pragma unroll
            for (int u = 0; u < 4; ++u) {
                float4 v = *(const float4*)&agg[tgt][q4 * 16 + u * 4];
                xp[(size_t)(u * 4 + 0) * hw] = v.x;
                xp[(size_t)(u * 4 + 1) * hw] = v.y;
                xp[(size_t)(u * 4 + 2) * hw] = v.z;
                xp[(size_t)(u * 4 + 3) * hw] = v.w;
            }
        }
    }
}

extern "C" void kernel_launch(void* const* d_in, const int* in_sizes, int n_in,
                              void* d_out, int out_size, void* d_ws, size_t ws_size,
                              hipStream_t stream) {
    const float* x             = (const float*)d_in[0];
    const float* ptx           = (const float*)d_in[1];
    const float* sm_w          = (const float*)d_in[2];
    // d_in[3] = sm_b: segment-constant logit shift, cancels in softmax
    const float* fo_w          = (const float*)d_in[4];
    const float* fo_b          = (const float*)d_in[5];
    const int*   point_key     = (const int*)d_in[6];
    const int*   pixel_tgt_idx = (const int*)d_in[7];

    const int x_elems = in_sizes[0];          // 64 * H * W
    const int hw      = x_elems / 64;
    const int n_tgt   = in_sizes[7];
    const int n_pts   = in_sizes[1] / 64;

    float* xout    = (float*)d_out;
    float* ptx_out = xout + (size_t)x_elems;

    const int n4 = x_elems / 4;
    copy_x_kernel<<<(n4 + 255) / 256, 256, 0, stream>>>(
        (const float4*)x, (float4*)xout, n4);

    const int blocks = (n_tgt + TB - 1) / TB;
    fused_kernel<<<blocks, 256, 0, stream>>>(
        x, ptx, sm_w, fo_w, fo_b, point_key, pixel_tgt_idx,
        xout, ptx_out, n_tgt, n_pts, hw);
}